// Round 11
// baseline (118.982 us; speedup 1.0000x reference)
//
#include <hip/hip_runtime.h>

namespace {

constexpr int B = 4;
constexpr int N = 8192;          // power of two (N = 1<<13)
constexpr int E = 24576;
constexpr int BN = B * N;
constexpr int BE = B * E;
constexpr int CHUNK = 256;       // staged points per wave-unit
constexpr int SUB = 64;          // argmin subblock granularity (matches rescan wave)
constexpr int RT = 4;            // rows per thread -> 8192 units / 2048 blocks

typedef float f32x2 __attribute__((ext_vector_type(2)));

// Monotonic float <-> uint mapping (total order matches float compare)
__device__ __forceinline__ unsigned fkey(float f) {
  unsigned b = __float_as_uint(f);
  return b ^ ((b & 0x80000000u) ? 0xFFFFFFFFu : 0x80000000u);
}
__device__ __forceinline__ float funkey(unsigned k) {
  unsigned b = k ^ ((k & 0x80000000u) ? 0x80000000u : 0xFFFFFFFFu);
  return __uint_as_float(b);
}
// 3-input min in one instruction (T17)
__device__ __forceinline__ float min3f(float a, float b, float c) {
  float d;
  asm("v_min3_f32 %0, %1, %2, %3" : "=v"(d) : "v"(a), "v"(b), "v"(c));
  return d;
}
// packed 2xf32 fma with the staged (wave-uniform) operand in SGPRs:
// one scalar operand per VALU inst is architecturally allowed.
__device__ __forceinline__ f32x2 pk_fma_vsv(f32x2 a, f32x2 bs, f32x2 c) {
  f32x2 d;
  asm("v_pk_fma_f32 %0, %1, %2, %3" : "=v"(d) : "v"(a), "s"(bs), "v"(c));
  return d;
}

// sums layout (floats): [0]=s1, [1]=s2, [2]=cos sum, [3..14]=nsq[b][d], [15..26]=vsq[b][d]

// A[i] = (-2*p, |p|^2) etc; A2/G2 = pair-packed: for pair p (points 2p,2p+1):
//   float4[2p]   = (x_{2p}, x_{2p+1}, y_{2p}, y_{2p+1})
//   float4[2p+1] = (z_{2p}, z_{2p+1}, w_{2p}, w_{2p+1})
__global__ __launch_bounds__(256) void prep_kernel(const float* __restrict__ preds,
                                                   const float* __restrict__ gts,
                                                   float4* __restrict__ A,
                                                   float4* __restrict__ G,
                                                   float* __restrict__ A2f,
                                                   float* __restrict__ G2f,
                                                   unsigned long long* __restrict__ m2,
                                                   unsigned* __restrict__ m1,
                                                   float* __restrict__ sums) {
  int i = blockIdx.x * 256 + threadIdx.x;
  float px = preds[3*i], py = preds[3*i+1], pz = preds[3*i+2];
  float gx = gts[3*i],   gy = gts[3*i+1],  gz = gts[3*i+2];
  float ax = -2.f*px, ay = -2.f*py, az = -2.f*pz, aw = px*px + py*py + pz*pz;
  float bx = -2.f*gx, by = -2.f*gy, bz = -2.f*gz, bw = gx*gx + gy*gy + gz*gz;
  A[i] = make_float4(ax, ay, az, aw);
  G[i] = make_float4(bx, by, bz, bw);
  int p8 = (i >> 1) * 8, l = i & 1;
  A2f[p8 + 0 + l] = ax; A2f[p8 + 2 + l] = ay; A2f[p8 + 4 + l] = az; A2f[p8 + 6 + l] = aw;
  G2f[p8 + 0 + l] = bx; G2f[p8 + 2 + l] = by; G2f[p8 + 4 + l] = bz; G2f[p8 + 6 + l] = bw;
  m2[i] = ~0ULL;
  m1[i] = 0xFFFFFFFFu;
  if (i < 32) sums[i] = 0.f;
}

// Barrier-free, LDS-free min pass. Each WAVE owns one unit:
//   unit u: ck = u&31 (chunk), rg = (u>>5)&31 (256-row group), b = (u>>10)&3, which = u>>12
//   which=0: rows = gts, staged = preds(A2) -> m2 (min over m + subblock argmin)
//   which=1: rows = preds, staged = gts(G2) -> m1 (min over n)
// Staged records are wave-uniform -> scalar s_load path; every pk_fma takes the
// record as its one allowed SGPR operand (only qw needs a VGPR copy).
// Packed fma chain order == rescan's scalar fmaf chain (bitwise identical).
__global__ __launch_bounds__(256) void pass_wave(const float4* __restrict__ A,
                                                 const float4* __restrict__ G,
                                                 const float4* __restrict__ A2,
                                                 const float4* __restrict__ G2,
                                                 unsigned long long* __restrict__ m2,
                                                 unsigned* __restrict__ m1) {
  const int wid  = __builtin_amdgcn_readfirstlane((int)(threadIdx.x >> 6));
  const int lane = threadIdx.x & 63;
  const int u    = blockIdx.x * 4 + wid;
  const int ck = u & 31, rg = (u >> 5) & 31, b = (u >> 10) & 3, which = u >> 12;
  const float4* __restrict__ R  = which ? A  : G;
  const float4* __restrict__ S2 = which ? G2 : A2;
  const float4* __restrict__ Sg = S2 + b * N + ck * CHUNK;  // uniform base
  const int base = ck * CHUNK;
  f32x2 x2[RT], y2[RT], z2[RT];
  float w[RT], best[RT];
  int sbb[RT];
#pragma unroll
  for (int i = 0; i < RT; ++i) {
    float4 r = R[b * N + rg * (64 * RT) + i * 64 + lane];
    float xx = -0.5f * r.x, yy = -0.5f * r.y, zz = -0.5f * r.z;
    x2[i] = f32x2{xx, xx}; y2[i] = f32x2{yy, yy}; z2[i] = f32x2{zz, zz};
    w[i] = r.w; best[i] = 3.4e38f; sbb[i] = 0;
  }
  for (int sb = 0; sb < CHUNK; sb += SUB) {
    float a[RT];
#pragma unroll
    for (int i = 0; i < RT; ++i) a[i] = 3.4e38f;
    const float4* Sp = Sg + sb;
#pragma unroll 8
    for (int jr = 0; jr < SUB / 2; ++jr) {     // 32 pair-records of 2 points
      float4 qa = Sp[2*jr], qb = Sp[2*jr + 1]; // uniform -> s_load path
      f32x2 qx = f32x2{qa.x, qa.y}, qy = f32x2{qa.z, qa.w};
      f32x2 qz = f32x2{qb.x, qb.y}, qw = f32x2{qb.z, qb.w};
#pragma unroll
      for (int i = 0; i < RT; ++i) {
        f32x2 t = pk_fma_vsv(z2[i], qz, qw);   // qw: one v_mov_b64 per record-pair
        t = pk_fma_vsv(y2[i], qy, t);
        t = pk_fma_vsv(x2[i], qx, t);
        a[i] = min3f(a[i], t.x, t.y);
      }
    }
#pragma unroll
    for (int i = 0; i < RT; ++i)
      if (a[i] < best[i]) { best[i] = a[i]; sbb[i] = base + sb; }  // strict <: earliest subblock wins ties
  }
#pragma unroll
  for (int i = 0; i < RT; ++i) {
    const int gi = b * N + rg * (64 * RT) + i * 64 + lane;
    float d = w[i] + best[i];
    if (which == 0) {
      atomicMin(&m2[gi], ((unsigned long long)fkey(d) << 32) | (unsigned)sbb[i]);
    } else {
      atomicMin(&m1[gi], fkey(d));
    }
  }
}

// post: 2048 blocks. Each wave re-scans 4 rows' winning 64-pt subblocks
// (bitwise-identical scalar fmaf chain, ballot -> first match) AND accumulates
// the block's contribution to sum(mins1), sum(mins2) (keys already in hand).
__global__ __launch_bounds__(256) void post_kernel(const float4* __restrict__ G,
                                                   const float4* __restrict__ A,
                                                   const unsigned long long* __restrict__ m2,
                                                   const unsigned* __restrict__ m1,
                                                   unsigned* __restrict__ nidx,
                                                   float* __restrict__ sums) {
  __shared__ float ls1[4], ls2[4];
  const int wid  = threadIdx.x >> 6;
  const int lane = threadIdx.x & 63;
  const int row0 = (blockIdx.x * 4 + wid) * 4;
  unsigned long long p[4];
  float4 r[4];
#pragma unroll
  for (int j = 0; j < 4; ++j) p[j] = m2[row0 + j];   // uniform -> s_load, issued first
#pragma unroll
  for (int j = 0; j < 4; ++j) r[j] = G[row0 + j];
  float s1 = 0.f, s2 = 0.f;
#pragma unroll
  for (int j = 0; j < 4; ++j) {
    const int gi = row0 + j;
    const int b = gi >> 13;
    const unsigned kd = (unsigned)(p[j] >> 32);
    const int base = (int)(unsigned)p[j];
    const float x = -0.5f*r[j].x, y = -0.5f*r[j].y, z = -0.5f*r[j].z, w = r[j].w;
    float4 q = A[b * N + base + lane];
    float v = fmaf(x, q.x, fmaf(y, q.y, fmaf(z, q.z, q.w)));
    float d = w + v;
    unsigned long long mask = __ballot(fkey(d) == kd);
    if (lane == 0) nidx[gi] = mask ? (unsigned)(base + __ffsll(mask) - 1) : (unsigned)base;
    s2 += funkey(kd);
    s1 += funkey(m1[gi]);                              // uniform -> s_load
  }
  if (lane == 0) { ls1[wid] = s1; ls2[wid] = s2; }
  __syncthreads();
  if (threadIdx.x == 0) {
    atomicAdd(&sums[0], ls1[0] + ls1[1] + ls1[2] + ls1[3]);
    atomicAdd(&sums[1], ls2[0] + ls2[1] + ls2[2] + ls2[3]);
  }
}

// edge1: per-edge gathers once; store SoA (v,n) for edge2; all 6 column sums
// in ONE LDS round (2 barriers, 6 atomics per block).
__global__ __launch_bounds__(256) void edge1_kernel(const float* __restrict__ preds,
                                                    const float* __restrict__ normals,
                                                    const int* __restrict__ edges,
                                                    const unsigned* __restrict__ nidx,
                                                    float* __restrict__ ev,
                                                    float* __restrict__ sums) {
  __shared__ float ws[4][6];
  const int b = blockIdx.y;
  const int e = blockIdx.x * 256 + threadIdx.x;
  const int wid = threadIdx.x >> 6, lane = threadIdx.x & 63;
  int e0 = edges[2*e], e1 = edges[2*e+1];
  const float* pb = preds   + 3*(size_t)b*N;
  const float* nb = normals + 3*(size_t)b*N;
  float vx = pb[3*e0]   - pb[3*e1];
  float vy = pb[3*e0+1] - pb[3*e1+1];
  float vz = pb[3*e0+2] - pb[3*e1+2];
  unsigned ni = nidx[b*N + e0];
  float nx = nb[3*ni], ny = nb[3*ni+1], nz = nb[3*ni+2];
  const int be = b * E + e;
  ev[0*BE + be] = vx; ev[1*BE + be] = vy; ev[2*BE + be] = vz;
  ev[3*BE + be] = nx; ev[4*BE + be] = ny; ev[5*BE + be] = nz;
  float v[6] = {nx*nx, ny*ny, nz*nz, vx*vx, vy*vy, vz*vz};
#pragma unroll
  for (int k = 0; k < 6; ++k)
#pragma unroll
    for (int o = 32; o; o >>= 1) v[k] += __shfl_down(v[k], o, 64);
  if (lane == 0) {
#pragma unroll
    for (int k = 0; k < 6; ++k) ws[wid][k] = v[k];
  }
  __syncthreads();
  if (threadIdx.x < 6) {
    const int k = threadIdx.x;
    float t = ws[0][k] + ws[1][k] + ws[2][k] + ws[3][k];
    atomicAdd(&sums[(k < 3 ? 3 + k : 12 + k) + b*3], t);   // nsq: 3+b*3+d, vsq: 15+b*3+d
  }
}

// edge2: coalesced SoA reads, norms from sums (broadcast), 1 reduce, 1 atomic.
__global__ __launch_bounds__(256) void edge2_kernel(const float* __restrict__ ev,
                                                    float* __restrict__ sums) {
  __shared__ float ws[4];
  const int b = blockIdx.y;
  const int e = blockIdx.x * 256 + threadIdx.x;
  const int be = b * E + e;
  float vx = ev[0*BE + be], vy = ev[1*BE + be], vz = ev[2*BE + be];
  float nx = ev[3*BE + be], ny = ev[4*BE + be], nz = ev[5*BE + be];
  float inn0 = 1.f / fmaxf(sqrtf(sums[3  + b*3 + 0]), 1e-12f);
  float inn1 = 1.f / fmaxf(sqrtf(sums[3  + b*3 + 1]), 1e-12f);
  float inn2 = 1.f / fmaxf(sqrtf(sums[3  + b*3 + 2]), 1e-12f);
  float inv0 = 1.f / fmaxf(sqrtf(sums[15 + b*3 + 0]), 1e-12f);
  float inv1 = 1.f / fmaxf(sqrtf(sums[15 + b*3 + 1]), 1e-12f);
  float inv2 = 1.f / fmaxf(sqrtf(sums[15 + b*3 + 2]), 1e-12f);
  float c = fabsf(nx*inn0*vx*inv0 + ny*inn1*vy*inv1 + nz*inn2*vz*inv2);
#pragma unroll
  for (int o = 32; o; o >>= 1) c += __shfl_down(c, o, 64);
  if ((threadIdx.x & 63) == 0) ws[threadIdx.x >> 6] = c;
  __syncthreads();
  if (threadIdx.x == 0) atomicAdd(&sums[2], ws[0] + ws[1] + ws[2] + ws[3]);
}

__global__ void final_kernel(const float* __restrict__ sums, float* __restrict__ out) {
  if (threadIdx.x == 0 && blockIdx.x == 0) {
    float esum = 0.f;
#pragma unroll
    for (int i = 0; i < 12; ++i) esum += sums[15 + i];
    float chamfer   = (sums[0] + sums[1]) * (1.f / (float)BN);
    float edge_loss = esum * (1.f / (float)(B * E));
    float ncl       = sums[2] * (1.f / (float)(B * E));
    out[0] = 30000.f * chamfer + 240.f * edge_loss + 200000.f * ncl;
  }
}

} // namespace

extern "C" void kernel_launch(void* const* d_in, const int* in_sizes, int n_in,
                              void* d_out, int out_size, void* d_ws, size_t ws_size,
                              hipStream_t stream) {
  (void)in_sizes; (void)n_in; (void)out_size; (void)ws_size;
  const float* preds   = (const float*)d_in[0];
  const float* gts     = (const float*)d_in[1];
  const float* normals = (const float*)d_in[2];
  const int*   edges   = (const int*)d_in[3];
  char* ws = (char*)d_ws;
  // ws layout (16B aligned): A 512K | G 512K | A2 512K | G2 512K | m2 256K | m1 128K |
  //                          nidx 128K | sums 128B.. | ev 2.25M (6 x BE floats)
  float4*             A    = (float4*)(ws);
  float4*             G    = (float4*)(ws + 0x080000);
  float4*             A2   = (float4*)(ws + 0x100000);
  float4*             G2   = (float4*)(ws + 0x180000);
  unsigned long long* m2   = (unsigned long long*)(ws + 0x200000);
  unsigned*           m1   = (unsigned*)(ws + 0x240000);
  unsigned*           nidx = (unsigned*)(ws + 0x260000);
  float*              sums = (float*)(ws + 0x280000);
  float*              ev   = (float*)(ws + 0x281000);
  float* out = (float*)d_out;

  prep_kernel<<<dim3(BN/256), 256, 0, stream>>>(preds, gts, A, G, (float*)A2, (float*)G2,
                                                m2, m1, sums);
  // 8192 wave-units (2 passes x 4 b x 32 rowgroups x 32 chunks), 4 waves/block
  pass_wave<<<dim3(2048), 256, 0, stream>>>(A, G, A2, G2, m2, m1);
  // rescan + chamfer reduce fused: 2048 blocks, 16 rows each
  post_kernel<<<dim3(2048), 256, 0, stream>>>(G, A, m2, m1, nidx, sums);
  edge1_kernel<<<dim3(E/256, B), 256, 0, stream>>>(preds, normals, edges, nidx, ev, sums);
  edge2_kernel<<<dim3(E/256, B), 256, 0, stream>>>(ev, sums);
  final_kernel<<<1, 64, 0, stream>>>(sums, out);
}

// Round 12
// 74.107 us; speedup vs baseline: 1.6055x; 1.6055x over previous
//
#include <hip/hip_runtime.h>

namespace {

constexpr int B = 4;
constexpr int N = 8192;          // power of two (N = 1<<13)
constexpr int E = 24576;
constexpr int BN = B * N;
constexpr int BE = B * E;
constexpr int CHUNK = 256;       // staged points per wave-unit
constexpr int RT = 4;            // rows per thread -> 8192 units / 2048 blocks

typedef float f32x2 __attribute__((ext_vector_type(2)));

// Monotonic float <-> uint mapping (total order matches float compare)
__device__ __forceinline__ unsigned fkey(float f) {
  unsigned b = __float_as_uint(f);
  return b ^ ((b & 0x80000000u) ? 0xFFFFFFFFu : 0x80000000u);
}
__device__ __forceinline__ float funkey(unsigned k) {
  unsigned b = k ^ ((k & 0x80000000u) ? 0x80000000u : 0xFFFFFFFFu);
  return __uint_as_float(b);
}
// 3-input min in one instruction (T17)
__device__ __forceinline__ float min3f(float a, float b, float c) {
  float d;
  asm("v_min3_f32 %0, %1, %2, %3" : "=v"(d) : "v"(a), "v"(b), "v"(c));
  return d;
}
// packed 2xf32 fma with the staged (wave-uniform) operand in SGPRs
__device__ __forceinline__ f32x2 pk_fma_vsv(f32x2 a, f32x2 bs, f32x2 c) {
  f32x2 d;
  asm("v_pk_fma_f32 %0, %1, %2, %3" : "=v"(d) : "v"(a), "s"(bs), "v"(c));
  return d;
}
// packed 2xf32 fma, all-VGPR (for the per-lane argmin epilogue re-compute;
// same instruction & operand order as pk_fma_vsv -> bitwise identical result)
__device__ __forceinline__ f32x2 pk_fma_vvv(f32x2 a, f32x2 b, f32x2 c) {
  f32x2 d;
  asm("v_pk_fma_f32 %0, %1, %2, %3" : "=v"(d) : "v"(a), "v"(b), "v"(c));
  return d;
}

// sums layout (floats): [0]=s1, [1]=s2, [2]=cos sum, [3..14]=nsq[b][d], [15..26]=vsq[b][d]

// A[i] = (-2*p, |p|^2) etc; A2/G2 = pair-packed: for pair p (points 2p,2p+1):
//   float4[2p]   = (x_{2p}, x_{2p+1}, y_{2p}, y_{2p+1})
//   float4[2p+1] = (z_{2p}, z_{2p+1}, w_{2p}, w_{2p+1})
__global__ __launch_bounds__(256) void prep_kernel(const float* __restrict__ preds,
                                                   const float* __restrict__ gts,
                                                   float4* __restrict__ A,
                                                   float4* __restrict__ G,
                                                   float* __restrict__ A2f,
                                                   float* __restrict__ G2f,
                                                   unsigned long long* __restrict__ m2,
                                                   unsigned* __restrict__ m1,
                                                   float* __restrict__ sums) {
  int i = blockIdx.x * 256 + threadIdx.x;
  float px = preds[3*i], py = preds[3*i+1], pz = preds[3*i+2];
  float gx = gts[3*i],   gy = gts[3*i+1],  gz = gts[3*i+2];
  float ax = -2.f*px, ay = -2.f*py, az = -2.f*pz, aw = px*px + py*py + pz*pz;
  float bx = -2.f*gx, by = -2.f*gy, bz = -2.f*gz, bw = gx*gx + gy*gy + gz*gz;
  A[i] = make_float4(ax, ay, az, aw);
  G[i] = make_float4(bx, by, bz, bw);
  int p8 = (i >> 1) * 8, l = i & 1;
  A2f[p8 + 0 + l] = ax; A2f[p8 + 2 + l] = ay; A2f[p8 + 4 + l] = az; A2f[p8 + 6 + l] = aw;
  G2f[p8 + 0 + l] = bx; G2f[p8 + 2 + l] = by; G2f[p8 + 4 + l] = bz; G2f[p8 + 6 + l] = bw;
  m2[i] = ~0ULL;
  m1[i] = 0xFFFFFFFFu;
  if (i < 32) sums[i] = 0.f;
}

// Barrier-free, LDS-free min pass. Each WAVE owns one unit:
//   unit u: ck = u&31 (chunk), rg = (u>>5)&31 (256-row group), b = (u>>10)&3, which = u>>12
//   which=0: rows = gts, staged = preds(A2) -> m2, with EXACT inline argmin:
//     per record-pair track winner via (min3, v_cmp, v_cndmask); strict-decrease
//     keeps the FIRST (lowest-index) winner; epilogue disambiguates the 2 points
//     of the winning record with an identical pk re-compute (t.x<=t.y -> lower idx).
//     u64 atomicMin on (fkey(d)<<32 | exact_idx) => global first-min semantics.
//   which=1: rows = preds, staged = gts(G2) -> m1 (min only, 4-inst loop).
// Staged records are wave-uniform -> scalar s_load path; pk_fma takes the record
// as its one allowed SGPR operand. This removes the rescan kernel entirely
// (R3-R11: rescan cost ~35-56us at ~2% VALUBusy, unexplained latency).
__global__ __launch_bounds__(256) void pass_wave(const float4* __restrict__ A,
                                                 const float4* __restrict__ G,
                                                 const float4* __restrict__ A2,
                                                 const float4* __restrict__ G2,
                                                 unsigned long long* __restrict__ m2,
                                                 unsigned* __restrict__ m1) {
  const int wid  = __builtin_amdgcn_readfirstlane((int)(threadIdx.x >> 6));
  const int lane = threadIdx.x & 63;
  const int u    = blockIdx.x * 4 + wid;
  const int ck = u & 31, rg = (u >> 5) & 31, b = (u >> 10) & 3, which = u >> 12;
  const float4* __restrict__ R  = which ? A  : G;
  const float4* __restrict__ S2 = which ? G2 : A2;
  const float4* __restrict__ Sg = S2 + b * N + ck * CHUNK;  // uniform base
  const int base = ck * CHUNK;
  f32x2 x2[RT], y2[RT], z2[RT];
  float w[RT], best[RT];
#pragma unroll
  for (int i = 0; i < RT; ++i) {
    float4 r = R[b * N + rg * (64 * RT) + i * 64 + lane];
    float xx = -0.5f * r.x, yy = -0.5f * r.y, zz = -0.5f * r.z;
    x2[i] = f32x2{xx, xx}; y2[i] = f32x2{yy, yy}; z2[i] = f32x2{zz, zz};
    w[i] = r.w; best[i] = 3.4e38f;
  }
  if (which == 0) {
    int wjj[RT];
#pragma unroll
    for (int i = 0; i < RT; ++i) wjj[i] = 0;
#pragma unroll 8
    for (int jr = 0; jr < CHUNK / 2; ++jr) {   // 128 record-pairs of 2 points
      float4 qa = Sg[2*jr], qb = Sg[2*jr + 1]; // uniform -> s_load path
      f32x2 qx = f32x2{qa.x, qa.y}, qy = f32x2{qa.z, qa.w};
      f32x2 qz = f32x2{qb.x, qb.y}, qw = f32x2{qb.z, qb.w};
#pragma unroll
      for (int i = 0; i < RT; ++i) {
        f32x2 t = pk_fma_vsv(z2[i], qz, qw);
        t = pk_fma_vsv(y2[i], qy, t);
        t = pk_fma_vsv(x2[i], qx, t);
        float m = min3f(best[i], t.x, t.y);
        wjj[i] = (m < best[i]) ? 2*jr : wjj[i];   // strict <: first winner kept
        best[i] = m;
      }
    }
#pragma unroll
    for (int i = 0; i < RT; ++i) {
      // disambiguate the 2 points of the winning record (per-lane gather)
      float4 qa = Sg[wjj[i]], qb = Sg[wjj[i] + 1];
      f32x2 t = pk_fma_vvv(z2[i], f32x2{qb.x, qb.y}, f32x2{qb.z, qb.w});
      t = pk_fma_vvv(y2[i], f32x2{qa.z, qa.w}, t);
      t = pk_fma_vvv(x2[i], f32x2{qa.x, qa.y}, t);
      const int idx = base + wjj[i] + ((t.x <= t.y) ? 0 : 1);  // tie -> lower idx
      const int gi = b * N + rg * (64 * RT) + i * 64 + lane;
      float d = w[i] + best[i];
      atomicMin(&m2[gi], ((unsigned long long)fkey(d) << 32) | (unsigned)idx);
    }
  } else {
#pragma unroll 8
    for (int jr = 0; jr < CHUNK / 2; ++jr) {
      float4 qa = Sg[2*jr], qb = Sg[2*jr + 1];
      f32x2 qx = f32x2{qa.x, qa.y}, qy = f32x2{qa.z, qa.w};
      f32x2 qz = f32x2{qb.x, qb.y}, qw = f32x2{qb.z, qb.w};
#pragma unroll
      for (int i = 0; i < RT; ++i) {
        f32x2 t = pk_fma_vsv(z2[i], qz, qw);
        t = pk_fma_vsv(y2[i], qy, t);
        t = pk_fma_vsv(x2[i], qx, t);
        best[i] = min3f(best[i], t.x, t.y);
      }
    }
#pragma unroll
    for (int i = 0; i < RT; ++i) {
      const int gi = b * N + rg * (64 * RT) + i * 64 + lane;
      atomicMin(&m1[gi], fkey(w[i] + best[i]));
    }
  }
}

__device__ __forceinline__ float block_sum(float v, float* ws) {
#pragma unroll
  for (int o = 32; o; o >>= 1) v += __shfl_down(v, o, 64);
  __syncthreads();
  if ((threadIdx.x & 63) == 0) ws[threadIdx.x >> 6] = v;
  __syncthreads();
  return ws[0] + ws[1] + ws[2] + ws[3];
}

// post: 128 blocks (R1-proven structure). nidx copy + chamfer reduce.
__global__ __launch_bounds__(256) void post_kernel(const unsigned long long* __restrict__ m2,
                                                   const unsigned* __restrict__ m1,
                                                   unsigned* __restrict__ nidx,
                                                   float* __restrict__ sums) {
  __shared__ float ws[4];
  int i = blockIdx.x * 256 + threadIdx.x;
  unsigned long long p = m2[i];
  nidx[i] = (unsigned)p;
  float d2 = funkey((unsigned)(p >> 32));
  float d1 = funkey(m1[i]);
  float s2 = block_sum(d2, ws);
  float s1 = block_sum(d1, ws);
  if (threadIdx.x == 0) { atomicAdd(&sums[1], s2); atomicAdd(&sums[0], s1); }
}

// edge1: per-edge gathers once; store SoA (v,n) for edge2; all 6 column sums
// in ONE LDS round (2 barriers, 6 atomics per block).
__global__ __launch_bounds__(256) void edge1_kernel(const float* __restrict__ preds,
                                                    const float* __restrict__ normals,
                                                    const int* __restrict__ edges,
                                                    const unsigned* __restrict__ nidx,
                                                    float* __restrict__ ev,
                                                    float* __restrict__ sums) {
  __shared__ float ws[4][6];
  const int b = blockIdx.y;
  const int e = blockIdx.x * 256 + threadIdx.x;
  const int wid = threadIdx.x >> 6, lane = threadIdx.x & 63;
  int e0 = edges[2*e], e1 = edges[2*e+1];
  const float* pb = preds   + 3*(size_t)b*N;
  const float* nb = normals + 3*(size_t)b*N;
  float vx = pb[3*e0]   - pb[3*e1];
  float vy = pb[3*e0+1] - pb[3*e1+1];
  float vz = pb[3*e0+2] - pb[3*e1+2];
  unsigned ni = nidx[b*N + e0];
  float nx = nb[3*ni], ny = nb[3*ni+1], nz = nb[3*ni+2];
  const int be = b * E + e;
  ev[0*BE + be] = vx; ev[1*BE + be] = vy; ev[2*BE + be] = vz;
  ev[3*BE + be] = nx; ev[4*BE + be] = ny; ev[5*BE + be] = nz;
  float v[6] = {nx*nx, ny*ny, nz*nz, vx*vx, vy*vy, vz*vz};
#pragma unroll
  for (int k = 0; k < 6; ++k)
#pragma unroll
    for (int o = 32; o; o >>= 1) v[k] += __shfl_down(v[k], o, 64);
  if (lane == 0) {
#pragma unroll
    for (int k = 0; k < 6; ++k) ws[wid][k] = v[k];
  }
  __syncthreads();
  if (threadIdx.x < 6) {
    const int k = threadIdx.x;
    float t = ws[0][k] + ws[1][k] + ws[2][k] + ws[3][k];
    atomicAdd(&sums[(k < 3 ? 3 + k : 12 + k) + b*3], t);   // nsq: 3+b*3+d, vsq: 15+b*3+d
  }
}

// edge2: coalesced SoA reads, norms from sums (broadcast), 1 reduce, 1 atomic.
__global__ __launch_bounds__(256) void edge2_kernel(const float* __restrict__ ev,
                                                    float* __restrict__ sums) {
  __shared__ float ws[4];
  const int b = blockIdx.y;
  const int e = blockIdx.x * 256 + threadIdx.x;
  const int be = b * E + e;
  float vx = ev[0*BE + be], vy = ev[1*BE + be], vz = ev[2*BE + be];
  float nx = ev[3*BE + be], ny = ev[4*BE + be], nz = ev[5*BE + be];
  float inn0 = 1.f / fmaxf(sqrtf(sums[3  + b*3 + 0]), 1e-12f);
  float inn1 = 1.f / fmaxf(sqrtf(sums[3  + b*3 + 1]), 1e-12f);
  float inn2 = 1.f / fmaxf(sqrtf(sums[3  + b*3 + 2]), 1e-12f);
  float inv0 = 1.f / fmaxf(sqrtf(sums[15 + b*3 + 0]), 1e-12f);
  float inv1 = 1.f / fmaxf(sqrtf(sums[15 + b*3 + 1]), 1e-12f);
  float inv2 = 1.f / fmaxf(sqrtf(sums[15 + b*3 + 2]), 1e-12f);
  float c = fabsf(nx*inn0*vx*inv0 + ny*inn1*vy*inv1 + nz*inn2*vz*inv2);
#pragma unroll
  for (int o = 32; o; o >>= 1) c += __shfl_down(c, o, 64);
  if ((threadIdx.x & 63) == 0) ws[threadIdx.x >> 6] = c;
  __syncthreads();
  if (threadIdx.x == 0) atomicAdd(&sums[2], ws[0] + ws[1] + ws[2] + ws[3]);
}

__global__ void final_kernel(const float* __restrict__ sums, float* __restrict__ out) {
  if (threadIdx.x == 0 && blockIdx.x == 0) {
    float esum = 0.f;
#pragma unroll
    for (int i = 0; i < 12; ++i) esum += sums[15 + i];
    float chamfer   = (sums[0] + sums[1]) * (1.f / (float)BN);
    float edge_loss = esum * (1.f / (float)(B * E));
    float ncl       = sums[2] * (1.f / (float)(B * E));
    out[0] = 30000.f * chamfer + 240.f * edge_loss + 200000.f * ncl;
  }
}

} // namespace

extern "C" void kernel_launch(void* const* d_in, const int* in_sizes, int n_in,
                              void* d_out, int out_size, void* d_ws, size_t ws_size,
                              hipStream_t stream) {
  (void)in_sizes; (void)n_in; (void)out_size; (void)ws_size;
  const float* preds   = (const float*)d_in[0];
  const float* gts     = (const float*)d_in[1];
  const float* normals = (const float*)d_in[2];
  const int*   edges   = (const int*)d_in[3];
  char* ws = (char*)d_ws;
  // ws layout (16B aligned): A 512K | G 512K | A2 512K | G2 512K | m2 256K | m1 128K |
  //                          nidx 128K | sums 128B.. | ev 2.25M (6 x BE floats)
  float4*             A    = (float4*)(ws);
  float4*             G    = (float4*)(ws + 0x080000);
  float4*             A2   = (float4*)(ws + 0x100000);
  float4*             G2   = (float4*)(ws + 0x180000);
  unsigned long long* m2   = (unsigned long long*)(ws + 0x200000);
  unsigned*           m1   = (unsigned*)(ws + 0x240000);
  unsigned*           nidx = (unsigned*)(ws + 0x260000);
  float*              sums = (float*)(ws + 0x280000);
  float*              ev   = (float*)(ws + 0x281000);
  float* out = (float*)d_out;

  prep_kernel<<<dim3(BN/256), 256, 0, stream>>>(preds, gts, A, G, (float*)A2, (float*)G2,
                                                m2, m1, sums);
  // 8192 wave-units (2 passes x 4 b x 32 rowgroups x 32 chunks), 4 waves/block
  pass_wave<<<dim3(2048), 256, 0, stream>>>(A, G, A2, G2, m2, m1);
  // nidx copy + chamfer reduce (128 blocks, R1-proven cheap tail)
  post_kernel<<<dim3(BN/256), 256, 0, stream>>>(m2, m1, nidx, sums);
  edge1_kernel<<<dim3(E/256, B), 256, 0, stream>>>(preds, normals, edges, nidx, ev, sums);
  edge2_kernel<<<dim3(E/256, B), 256, 0, stream>>>(ev, sums);
  final_kernel<<<1, 64, 0, stream>>>(sums, out);
}